// Round 12
// baseline (106.851 us; speedup 1.0000x reference)
//
#include <hip/hip_runtime.h>

typedef __bf16 bf16_t;
typedef __bf16 bf16x8 __attribute__((ext_vector_type(8)));
typedef __bf16 bf16x4 __attribute__((ext_vector_type(4)));
typedef float  f32x4  __attribute__((ext_vector_type(4)));

static constexpr int B_   = 2;
static constexpr int H_   = 48;
static constexpr int W_   = 48;
static constexpr int C_   = 512;
static constexpr int NH_  = 8;
static constexpr int HD_  = 64;
static constexpr int KW_  = 7;
static constexpr int ROWS_ = B_ * H_ * W_;    // 4608
static constexpr int QKVN_ = 3 * C_;          // 1536

// async global->LDS, 16B per lane; LDS dest = wave-uniform base + lane*16
#define GLDS16(g, l) __builtin_amdgcn_global_load_lds(                       \
    (const __attribute__((address_space(1))) void*)(g),                      \
    (__attribute__((address_space(3))) void*)(l), 16, 0, 0)

// fp32 -> bf16 pre-convert for x, qkv_w, proj_w
__global__ __launch_bounds__(256)
void convert_kernel(const float* __restrict__ x,  const float* __restrict__ qw,
                    const float* __restrict__ pw,
                    bf16_t* __restrict__ xb, bf16_t* __restrict__ qwb,
                    bf16_t* __restrict__ pwb)
{
    constexpr int NX = ROWS_ * C_;
    constexpr int NQ = QKVN_ * C_;
    constexpr int NP = C_ * C_;
    const int idx = (blockIdx.x * 256 + threadIdx.x) * 4;
    if (idx >= NX + NQ + NP) return;
    const float* src; bf16_t* dst; int off;
    if (idx < NX)           { src = x;  dst = xb;  off = idx; }
    else if (idx < NX + NQ) { src = qw; dst = qwb; off = idx - NX; }
    else                    { src = pw; dst = pwb; off = idx - NX - NQ; }
    const float4 v = *reinterpret_cast<const float4*>(src + off);
    bf16x4 o;
    o[0] = (bf16_t)v.x; o[1] = (bf16_t)v.y; o[2] = (bf16_t)v.z; o[3] = (bf16_t)v.w;
    *reinterpret_cast<bf16x4*>(dst + off) = o;
}

// C[m][n] = (sum_k A[m][k]*Wt[n][k] + bias[n]) * (n < scale_nlim ? scale : 1)
// KTILE=64, 256 threads = 4 waves. GLDS16 staging, xor-swizzled chunks:
// chunk slot s of row r holds global chunk s ^ (r&7) -> b128 frag reads are
// 2-way max (free per m136). Measured-best tiles: g1 128x64, g2 64x64
// (block count >= 2/CU beats per-block MFMA ratio at this size — R10).
template<int BM, int BN, int WMT, int WNT, typename OutT>
__global__ __launch_bounds__(256)
void gemm_bt(const bf16_t* __restrict__ A, const bf16_t* __restrict__ Wt,
             const float* __restrict__ bias, OutT* __restrict__ C,
             int M, int N, int K, float scale, int scale_nlim)
{
    constexpr int WCOLS = BN / (WNT * 16);
    __shared__ bf16_t Al[BM * 64];
    __shared__ bf16_t Bl[BN * 64];

    const int tid  = threadIdx.x;
    const int wave = tid >> 6;
    const int lane = tid & 63;
    const int bm = blockIdx.y * BM;
    const int bn = blockIdx.x * BN;
    const int wm = (wave / WCOLS) * (WMT * 16);
    const int wn = (wave % WCOLS) * (WNT * 16);
    const int n15 = lane & 15, q4 = lane >> 4, x7 = lane & 7;
    const int srow = lane >> 3, schunk = lane & 7;

    f32x4 acc[WMT][WNT] = {};

    for (int k0 = 0; k0 < K; k0 += 64) {
        __syncthreads();
        #pragma unroll
        for (int i = wave; i < BM / 8; i += 4) {
            const int row = i * 8 + srow;
            const int cg = schunk ^ (row & 7);
            GLDS16(A + (size_t)(bm + row) * K + k0 + cg * 8, Al + i * 512);
        }
        #pragma unroll
        for (int i = wave; i < BN / 8; i += 4) {
            const int row = i * 8 + srow;
            const int cg = schunk ^ (row & 7);
            GLDS16(Wt + (size_t)(bn + row) * K + k0 + cg * 8, Bl + i * 512);
        }
        __syncthreads();

        #pragma unroll
        for (int ks = 0; ks < 2; ++ks) {
            const int cl = (ks * 4 + q4) ^ x7;
            bf16x8 a[WMT], b[WNT];
            #pragma unroll
            for (int it = 0; it < WMT; ++it)
                a[it] = *reinterpret_cast<const bf16x8*>(
                    Al + (wm + it * 16 + n15) * 64 + cl * 8);
            #pragma unroll
            for (int jt = 0; jt < WNT; ++jt)
                b[jt] = *reinterpret_cast<const bf16x8*>(
                    Bl + (wn + jt * 16 + n15) * 64 + cl * 8);
            #pragma unroll
            for (int it = 0; it < WMT; ++it)
                #pragma unroll
                for (int jt = 0; jt < WNT; ++jt)
                    acc[it][jt] = __builtin_amdgcn_mfma_f32_16x16x32_bf16(
                        a[it], b[jt], acc[it][jt], 0, 0, 0);
        }
    }

    // epilogue: C/D layout col = lane&15, row = (lane>>4)*4 + r
    #pragma unroll
    for (int jt = 0; jt < WNT; ++jt) {
        const int col = bn + wn + jt * 16 + n15;
        const float bv = bias[col];
        const float sc = (col < scale_nlim) ? scale : 1.0f;
        #pragma unroll
        for (int it = 0; it < WMT; ++it) {
            const int row0 = bm + wm + it * 16 + q4 * 4;
            #pragma unroll
            for (int r = 0; r < 4; ++r)
                C[(size_t)(row0 + r) * N + col] = (OutT)((acc[it][jt][r] + bv) * sc);
        }
    }
}

// ---------------- MFMA neighborhood attention (R7, measured best) ----------
// One block per (b, 8x8 pixel tile, head). 256 threads = 4 waves.
// Union window 14x14, 16-aligned k-index = wr*16+wc (wc 14,15 = clamp-dup
// pads, masked to P=0). K and V staged via async GLDS16 (zero VALU staging):
//   Kl[w][slot s] = K-chunk s ^ (w&7)                 (b128 B-frag reads)
//   Vl[w][slot s] = V-chunk s ^ ((w+(w>>3))&7)        (u16 gathers, 2-way max)
// S = Q.K^T (14 tiles x 2 ks), mask, exp (no max pass: |logit| bounded ~2,
// expf(-1e30)=0), P = e/sum -> LDS (aliases Kl), O^T = V^T.P^T.
static constexpr int WROW = 224;
static constexpr int PST  = 232;
static constexpr int R1B  = 64 * PST * 2;    // 29696: P region (Kl aliases)
static constexpr int R2B  = WROW * 64 * 2;   // 28672: Vl

__global__ __launch_bounds__(256)
void attn_mfma_kernel(const bf16_t* __restrict__ qkv, bf16_t* __restrict__ attn_out)
{
    int bid = blockIdx.x;
    const int h  = bid & 7;   bid >>= 3;
    const int tj = bid % 6;   bid /= 6;
    const int ti = bid % 6;   bid /= 6;
    const int b  = bid;

    const int tid = threadIdx.x;
    const int wave = tid >> 6;
    const int lane = tid & 63;
    const int n15 = lane & 15, q4 = lane >> 4, x7 = lane & 7;

    const int gi0 = ti * 8, gj0 = tj * 8;
    const int si0 = min(max(gi0 - 3, 0), H_ - 14);
    const int sj0 = min(max(gj0 - 3, 0), W_ - 14);

    __shared__ char smem[R1B + R2B];
    bf16_t* Kl = (bf16_t*)smem;
    bf16_t* P  = (bf16_t*)smem;
    bf16_t* Vl = (bf16_t*)(smem + R1B);

    for (int i = wave; i < WROW / 8; i += 4) {
        const int row = i * 8 + (lane >> 3);
        const int wr = row >> 4;
        const int wc = min(row & 15, 13);
        const int gp = (b * H_ + si0 + wr) * W_ + sj0 + wc;
        const bf16_t* gbase = qkv + (size_t)gp * QKVN_ + h * HD_;
        const int cgk = (lane & 7) ^ (row & 7);
        GLDS16(gbase + C_ + cgk * 8, Kl + i * 512);
        const int cgv = (lane & 7) ^ ((row + (row >> 3)) & 7);
        GLDS16(gbase + 2 * C_ + cgv * 8, Vl + i * 512);
    }

    const int pixq = wave * 16 + n15;
    const int gpq = (b * H_ + gi0 + (pixq >> 3)) * W_ + gj0 + (pixq & 7);
    bf16x8 aq[2];
    #pragma unroll
    for (int ks = 0; ks < 2; ++ks)
        aq[ks] = *reinterpret_cast<const bf16x8*>(
            qkv + (size_t)gpq * QKVN_ + h * HD_ + ks * 32 + q4 * 8);

    __syncthreads();

    f32x4 S[14] = {};
    #pragma unroll
    for (int j = 0; j < 14; ++j) {
        #pragma unroll
        for (int ks = 0; ks < 2; ++ks) {
            const int cl = (ks * 4 + q4) ^ x7;
            const bf16x8 bk = *reinterpret_cast<const bf16x8*>(
                Kl + (j * 16 + n15) * 64 + cl * 8);
            S[j] = __builtin_amdgcn_mfma_f32_16x16x32_bf16(aq[ks], bk, S[j], 0, 0, 0);
        }
    }

    int ri[4], cj[4];
    #pragma unroll
    for (int r = 0; r < 4; ++r) {
        const int pix = wave * 16 + q4 * 4 + r;
        const int gi = gi0 + (pix >> 3), gj = gj0 + (pix & 7);
        ri[r] = min(max(gi - 3, 0), H_ - KW_) - si0;
        cj[r] = min(max(gj - 3, 0), W_ - KW_) - sj0;
    }
    #pragma unroll
    for (int j = 0; j < 14; ++j)
        #pragma unroll
        for (int r = 0; r < 4; ++r) {
            const bool valid = ((unsigned)(j - ri[r]) < 7u) &&
                               ((unsigned)(n15 - cj[r]) < 7u);
            S[j][r] = valid ? S[j][r] : -1e30f;
        }

    #pragma unroll
    for (int j = 0; j < 14; ++j)
        #pragma unroll
        for (int r = 0; r < 4; ++r)
            S[j][r] = __expf(S[j][r]);
    float rinv[4];
    #pragma unroll
    for (int r = 0; r < 4; ++r) {
        float s = S[0][r];
        #pragma unroll
        for (int j = 1; j < 14; ++j) s += S[j][r];
        #pragma unroll
        for (int off = 1; off < 16; off <<= 1) s += __shfl_xor(s, off);
        rinv[r] = 1.0f / s;
    }

    __syncthreads();

    #pragma unroll
    for (int j = 0; j < 14; ++j)
        #pragma unroll
        for (int r = 0; r < 4; ++r)
            P[(wave * 16 + q4 * 4 + r) * PST + j * 16 + n15] =
                (bf16_t)(S[j][r] * rinv[r]);

    __syncthreads();

    const int Xv   = wave * 2 + (n15 >> 3);
    const int dlow = n15 & 7;
    f32x4 O[4] = {};
    #pragma unroll
    for (int ks = 0; ks < 7; ++ks) {
        bf16x8 av;
        #pragma unroll
        for (int u = 0; u < 8; ++u) {
            const int w = ks * 32 + q4 * 8 + u;
            const int slot = Xv ^ ((w + (w >> 3)) & 7);
            av[u] = Vl[w * 64 + slot * 8 + dlow];
        }
        #pragma unroll
        for (int j2 = 0; j2 < 4; ++j2) {
            const bf16x8 bp = *reinterpret_cast<const bf16x8*>(
                P + (j2 * 16 + n15) * PST + ks * 32 + q4 * 8);
            O[j2] = __builtin_amdgcn_mfma_f32_16x16x32_bf16(av, bp, O[j2], 0, 0, 0);
        }
    }

    #pragma unroll
    for (int j2 = 0; j2 < 4; ++j2) {
        const int pix = j2 * 16 + n15;
        const int grow = (b * H_ + gi0 + (pix >> 3)) * W_ + gj0 + (pix & 7);
        const int d0 = wave * 16 + q4 * 4;
        bf16x4 o;
        #pragma unroll
        for (int r = 0; r < 4; ++r) o[r] = (bf16_t)(O[j2][r]);
        *reinterpret_cast<bf16x4*>(attn_out + (size_t)grow * C_ + h * HD_ + d0) = o;
    }
}

extern "C" void kernel_launch(void* const* d_in, const int* in_sizes, int n_in,
                              void* d_out, int out_size, void* d_ws, size_t ws_size,
                              hipStream_t stream)
{
    const float* x      = (const float*)d_in[0];
    const float* qkv_w  = (const float*)d_in[1];
    const float* qkv_b  = (const float*)d_in[2];
    const float* proj_w = (const float*)d_in[3];
    const float* proj_b = (const float*)d_in[4];
    float* out = (float*)d_out;

    char* w = (char*)d_ws;
    bf16_t* xb    = (bf16_t*)w;  w += (size_t)ROWS_ * C_ * 2;
    bf16_t* qwb   = (bf16_t*)w;  w += (size_t)QKVN_ * C_ * 2;
    bf16_t* pwb   = (bf16_t*)w;  w += (size_t)C_ * C_ * 2;
    bf16_t* qkvb  = (bf16_t*)w;  w += (size_t)ROWS_ * QKVN_ * 2;
    bf16_t* attnb = (bf16_t*)w;

    // 0) fp32 -> bf16 casts
    constexpr int TOT4 = (ROWS_ * C_ + QKVN_ * C_ + C_ * C_) / 4;
    convert_kernel<<<(TOT4 + 255) / 256, 256, 0, stream>>>(x, qkv_w, proj_w, xb, qwb, pwb);

    // 1) QKV = x @ qkv_w.T + qkv_b ; q pre-scaled 0.125.  128x64 -> 864 blocks
    gemm_bt<128, 64, 4, 2, bf16_t><<<dim3(QKVN_ / 64, ROWS_ / 128), 256, 0, stream>>>(
        xb, qwb, qkv_b, qkvb, ROWS_, QKVN_, C_, 0.125f, C_);

    // 2) neighborhood attention (MFMA), 576 blocks
    attn_mfma_kernel<<<dim3(B_ * 6 * 6 * NH_), 256, 0, stream>>>(qkvb, attnb);

    // 3) out = attn @ proj_w.T + proj_b.  64x64 -> 576 blocks
    gemm_bt<64, 64, 2, 2, float><<<dim3(C_ / 64, ROWS_ / 64), 256, 0, stream>>>(
        attnb, pwb, proj_b, out, ROWS_, C_, C_, 1.0f, 0);
}